// Round 22
// baseline (246.824 us; speedup 1.0000x reference)
//
#include <hip/hip_runtime.h>
#include <hip/hip_bf16.h>

typedef __bf16 bf16x8 __attribute__((ext_vector_type(8)));
typedef float f32x4 __attribute__((ext_vector_type(4)));

static constexpr int B_ = 1024, S_ = 64, C_ = 512, E_ = 16, H_ = 1024, D_ = 256, V_ = 100;
static constexpr int NUMN = 32;

__device__ __forceinline__ unsigned short f2bf(float f) {
  union { float f; unsigned u; } x; x.f = f;
  unsigned r = x.u + 0x7fffu + ((x.u >> 16) & 1u);
  return (unsigned short)(r >> 16);
}

// Abramowitz-Stegun 7.1.26 erf, |err| <= 1.5e-7, branch-free, no libm call.
__device__ __forceinline__ float erf_fast(float x) {
  float ax = fabsf(x);
  float t = 1.0f / fmaf(0.3275911f, ax, 1.0f);
  float p = fmaf(1.061405429f, t, -1.453152027f);
  p = fmaf(p, t, 1.421413741f);
  p = fmaf(p, t, -0.284496736f);
  p = fmaf(p, t, 0.254829592f);
  p = p * t;
  float e = 1.0f - p * __expf(-ax * ax);
  return copysignf(e, x);
}

// ---------------- codec -> bf16  +  gate weight f64 conversion (merged) ----------------
__global__ __launch_bounds__(256) void k_codec_cvt(const float* __restrict__ src,
                                                   unsigned short* __restrict__ dst,
                                                   const float* __restrict__ gW2,
                                                   const float* __restrict__ gW1,
                                                   double* __restrict__ w2d,
                                                   double* __restrict__ w1ld,
                                                   int* __restrict__ flagcnt) {
  int i = blockIdx.x * 256 + threadIdx.x;
  if (i < B_ * C_) dst[i] = f2bf(src[i]);
  if (i < 4096) w2d[i] = (double)gW2[i];
  if (i < 256) w1ld[i] = (double)gW1[(size_t)(3 * C_) * 256 + i];
  if (i == 0) *flagcnt = 0;
}

// ---------------- batched transpose f32[K,N] -> bf16[N,K] ----------------
__global__ __launch_bounds__(256) void k_transpose_bf(const float* __restrict__ W,
                                                      unsigned short* __restrict__ WT,
                                                      int K, int N) {
  __shared__ float t[32][33];
  int e = blockIdx.z;
  const float* We = W + (size_t)e * K * N;
  unsigned short* Te = WT + (size_t)e * N * K;
  int n0 = blockIdx.x * 32, k0 = blockIdx.y * 32;
  int tx = threadIdx.x & 31, ty = threadIdx.x >> 5;  // 32 x 8
#pragma unroll
  for (int i = 0; i < 32; i += 8) t[ty + i][tx] = We[(size_t)(k0 + ty + i) * N + n0 + tx];
  __syncthreads();
#pragma unroll
  for (int i = 0; i < 32; i += 8)
    Te[(size_t)(n0 + ty + i) * K + k0 + tx] = f2bf(t[tx][ty + i]);
}

// ---------------- cW [n][d][v] f32 -> cwt [n][128][256] bf16 (v-padded) ----------------
__global__ __launch_bounds__(256) void k_cwt(const float* __restrict__ cW,
                                             unsigned short* __restrict__ cwt) {
  __shared__ float t[32][33];
  int n = blockIdx.z;
  const float* src = cW + (size_t)n * D_ * V_;
  unsigned short* dst = cwt + (size_t)n * 128 * 256;
  int v0 = blockIdx.x * 32, d0 = blockIdx.y * 32;
  int tx = threadIdx.x & 31, ty = threadIdx.x >> 5;  // 32 x 8
#pragma unroll
  for (int i = 0; i < 32; i += 8) {
    int v = v0 + tx;
    t[ty + i][tx] = (v < V_) ? src[(size_t)(d0 + ty + i) * V_ + v] : 0.f;
  }
  __syncthreads();
#pragma unroll
  for (int i = 0; i < 32; i += 8)
    dst[(size_t)(v0 + ty + i) * 256 + d0 + tx] = f2bf(t[tx][ty + i]);
}

// ---------------- gate: codec part, 4 batches per block (gW1 L2 traffic /4) ----------------
// Per-b accumulation order is bit-identical to the validated version
// (4-way k split a0..a3, final (a0+a1)+(a2+a3)).
__global__ __launch_bounds__(256) void k_codecpart(const float* __restrict__ codec,
                                                   const float* __restrict__ gW1,
                                                   double* __restrict__ cp) {
  int j = threadIdx.x;
  int b0 = blockIdx.x * 4;
  double a0[4] = {0, 0, 0, 0}, a1[4] = {0, 0, 0, 0}, a2[4] = {0, 0, 0, 0}, a3[4] = {0, 0, 0, 0};
  for (int k = 0; k < C_; k += 4) {
    double w0 = (double)gW1[(size_t)k * 256 + j];
    double w1 = (double)gW1[(size_t)(k + 1) * 256 + j];
    double w2 = (double)gW1[(size_t)(k + 2) * 256 + j];
    double w3 = (double)gW1[(size_t)(k + 3) * 256 + j];
#pragma unroll
    for (int bi = 0; bi < 4; ++bi) {
      const float* cb = codec + (size_t)(b0 + bi) * C_;
      a0[bi] += (double)cb[k] * w0;
      a1[bi] += (double)cb[k + 1] * w1;
      a2[bi] += (double)cb[k + 2] * w2;
      a3[bi] += (double)cb[k + 3] * w3;
    }
  }
#pragma unroll
  for (int bi = 0; bi < 4; ++bi)
    cp[(size_t)(b0 + bi) * 256 + j] = (a0[bi] + a1[bi]) + (a2[bi] + a3[bi]);
}

// ---------------- gate: pos+type partials, split-K (16 chunks of 32) ----------------
__global__ __launch_bounds__(256) void k_postype_part(const float* __restrict__ pos_emb,
                                                      const float* __restrict__ type_emb,
                                                      const float* __restrict__ gW1,
                                                      double* __restrict__ pp) {
  int j = threadIdx.x;
  int s = blockIdx.x;
  int kc = blockIdx.y;
  int tt = (s >= NUMN) ? 1 : 0;
  double a0 = 0, a1 = 0;
  int k0 = kc * 32;
  for (int kk = 0; kk < 32; kk += 2) {
    int k = k0 + kk;
    a0 += (double)pos_emb[(size_t)s * C_ + k] * (double)gW1[(size_t)(C_ + k) * 256 + j] +
          (double)type_emb[(size_t)tt * C_ + k] * (double)gW1[(size_t)(2 * C_ + k) * 256 + j];
    a1 += (double)pos_emb[(size_t)s * C_ + k + 1] * (double)gW1[(size_t)(C_ + k + 1) * 256 + j] +
          (double)type_emb[(size_t)tt * C_ + k + 1] * (double)gW1[(size_t)(2 * C_ + k + 1) * 256 + j];
  }
  pp[((size_t)kc * 64 + s) * 256 + j] = a0 + a1;
}

// ---------------- reduce partials + gb1 -> ptT [j][s] ----------------
__global__ __launch_bounds__(256) void k_postype_red(const double* __restrict__ pp,
                                                     const float* __restrict__ gb1,
                                                     double* __restrict__ ptT) {
  int j = threadIdx.x;
  int s = blockIdx.x;
  double acc = (double)gb1[j];
#pragma unroll
  for (int kc = 0; kc < 16; ++kc) acc += pp[((size_t)kc * 64 + s) * 256 + j];
  ptT[(size_t)j * 64 + s] = acc;
}

// ---------------- gate bulk: f32 logits + margin flagging (no fallback inline) ----------------
__global__ __launch_bounds__(256) void k_gate(const double* __restrict__ cp,
                                              const double* __restrict__ ptT,
                                              const float* __restrict__ gW2,
                                              const double* __restrict__ w1ld,
                                              const float* __restrict__ gb2,
                                              const int* __restrict__ mask,
                                              float* __restrict__ out_g,
                                              float* __restrict__ out_i,
                                              float* __restrict__ out_m,
                                              float* __restrict__ tg,
                                              int* __restrict__ ti,
                                              int* __restrict__ flagcnt,
                                              int* __restrict__ flaglist) {
  __shared__ float red[3][64][17];
  int b = blockIdx.x;
  int s = threadIdx.x & 63;
  int wv = __builtin_amdgcn_readfirstlane(threadIdx.x >> 6);  // 0..3
  int token = b * 64 + s;
  double mf = (double)mask[token];
  const double* cpb = cp + (size_t)b * 256;
  float acc[16];
#pragma unroll
  for (int e = 0; e < 16; ++e) acc[e] = 0.f;
#pragma unroll 2
  for (int jj = 0; jj < 64; ++jj) {
    int j = wv * 64 + jj;
    double xd = cpb[j] + ptT[(size_t)j * 64 + s] + mf * w1ld[j];
    float x = (float)xd;
    float ef = erf_fast(x * 0.70710678f);
    float h = 0.5f * x * (1.0f + ef);
    const float* w2 = gW2 + (size_t)j * 16;
#pragma unroll
    for (int e = 0; e < 16; ++e) acc[e] = fmaf(h, w2[e], acc[e]);
  }
  if (wv > 0) {
#pragma unroll
    for (int e = 0; e < 16; ++e) red[wv - 1][s][e] = acc[e];
  }
  __syncthreads();
  if (wv == 0) {
    double vp[16];
#pragma unroll
    for (int e = 0; e < 16; ++e)
      vp[e] = (double)((acc[e] + red[0][s][e]) + (red[1][s][e] + red[2][s][e])) + (double)gb2[e];
    // ---- decision margin ----
    double margin;
    if (mf == 0.0) {
      double mn = 1e300;
#pragma unroll
      for (int e = 0; e < 16; ++e) mn = fmin(mn, fabs(vp[e]));
      margin = mn;
    } else {
      double t1 = -1e300, t2 = -1e300, t3 = -1e300;
#pragma unroll
      for (int e = 0; e < 16; ++e) {
        double v = vp[e];
        if (v > t1) { t3 = t2; t2 = t1; t1 = v; }
        else if (v > t2) { t3 = t2; t2 = v; }
        else if (v > t3) { t3 = v; }
      }
      margin = fmin(t1 - t2, t2 - t3);
    }
    if (margin < 1e-4) {
      int idx = atomicAdd(flagcnt, 1);
      if (idx < 8192) flaglist[idx] = token;
    }
    // ---- selection (R6-validated logic) ----
    double v1, v2;
    int i1, i2;
    if (mf == 0.0) {
      int idx[2];
      int c = 0;
      for (int e = 0; e < 16 && c < 2; ++e)
        if (vp[e] > 0.0) idx[c++] = e;
      for (int e = 0; e < 16 && c < 2; ++e)
        if (!(vp[e] > 0.0)) idx[c++] = e;
      i1 = idx[0];
      i2 = idx[1];
      v1 = 0.0;
      v2 = 0.0;
    } else {
      v1 = -1e300; v2 = -1e300; i1 = 0; i2 = 1;
#pragma unroll
      for (int e = 0; e < 16; ++e) {
        double v = vp[e];
        if (v > v1) { v2 = v1; i2 = i1; v1 = v; i1 = e; }
        else if (v > v2) { v2 = v; i2 = e; }
      }
    }
    double ex = exp(v2 - v1);
    double den = 1.0 + ex;
    float g1 = (float)(1.0 / den), g2 = (float)(ex / den);
    out_g[(size_t)token * 2] = g1;
    out_g[(size_t)token * 2 + 1] = g2;
    out_i[(size_t)token * 2] = (float)i1;
    out_i[(size_t)token * 2 + 1] = (float)i2;
    out_m[token] = (float)mf;
    tg[(size_t)token * 2] = g1;
    tg[(size_t)token * 2 + 1] = g2;
    ti[(size_t)token * 2] = i1;
    ti[(size_t)token * 2 + 1] = i2;
  }
}

// ---------------- gate fix: exact f64 recompute of flagged tokens ----------------
__global__ __launch_bounds__(64) void k_gate_fix(const double* __restrict__ cp,
                                                 const double* __restrict__ ptT,
                                                 const double* __restrict__ w2d,
                                                 const double* __restrict__ w1ld,
                                                 const float* __restrict__ gb2,
                                                 const int* __restrict__ mask,
                                                 const int* __restrict__ flagcnt,
                                                 const int* __restrict__ flaglist,
                                                 float* __restrict__ out_g,
                                                 float* __restrict__ out_i,
                                                 float* __restrict__ out_m,
                                                 float* __restrict__ tg,
                                                 int* __restrict__ ti) {
  int cnt = *flagcnt;
  if (cnt > 8192) cnt = 8192;
  int lane = threadIdx.x;
  for (int fi = blockIdx.x; fi < cnt; fi += gridDim.x) {
    int token = flaglist[fi];
    int b = token >> 6, sf = token & 63;
    double mf = (double)mask[token];
    const double* cpb = cp + (size_t)b * 256;
    double facc[16];
#pragma unroll
    for (int e = 0; e < 16; ++e) facc[e] = 0.0;
#pragma unroll
    for (int jj = 0; jj < 4; ++jj) {
      int j = jj * 64 + lane;
      double x = cpb[j] + ptT[(size_t)j * 64 + sf] + mf * w1ld[j];
      double h = 0.5 * x * (1.0 + erf(x * 0.70710678118654752440));
      const double* w2 = w2d + (size_t)j * 16;
#pragma unroll
      for (int e = 0; e < 16; ++e) facc[e] += h * w2[e];
    }
#pragma unroll
    for (int off = 32; off >= 1; off >>= 1) {
#pragma unroll
      for (int e = 0; e < 16; ++e) facc[e] += __shfl_xor(facc[e], off, 64);
    }
    if (lane == 0) {
      double vp[16];
#pragma unroll
      for (int e = 0; e < 16; ++e) vp[e] = facc[e] + (double)gb2[e];
      double v1, v2;
      int i1, i2;
      if (mf == 0.0) {
        int idx[2];
        int c = 0;
        for (int e = 0; e < 16 && c < 2; ++e)
          if (vp[e] > 0.0) idx[c++] = e;
        for (int e = 0; e < 16 && c < 2; ++e)
          if (!(vp[e] > 0.0)) idx[c++] = e;
        i1 = idx[0];
        i2 = idx[1];
        v1 = 0.0;
        v2 = 0.0;
      } else {
        v1 = -1e300; v2 = -1e300; i1 = 0; i2 = 1;
#pragma unroll
        for (int e = 0; e < 16; ++e) {
          double v = vp[e];
          if (v > v1) { v2 = v1; i2 = i1; v1 = v; i1 = e; }
          else if (v > v2) { v2 = v; i2 = e; }
        }
      }
      double ex = exp(v2 - v1);
      double den = 1.0 + ex;
      float g1 = (float)(1.0 / den), g2 = (float)(ex / den);
      out_g[(size_t)token * 2] = g1;
      out_g[(size_t)token * 2 + 1] = g2;
      out_i[(size_t)token * 2] = (float)i1;
      out_i[(size_t)token * 2 + 1] = (float)i2;
      out_m[token] = (float)mf;
      tg[(size_t)token * 2] = g1;
      tg[(size_t)token * 2 + 1] = g2;
      ti[(size_t)token * 2] = i1;
      ti[(size_t)token * 2 + 1] = i2;
    }
  }
}

// ---------------- 256x256 MFMA GEMM: 16 waves (64x64 each), BK=64, dbuf, 1 drain/tile ----------------
__global__ __launch_bounds__(1024, 1) void k_gemm256(const unsigned short* __restrict__ A, size_t aStride,
                                                     const unsigned short* __restrict__ WT,
                                                     const float* __restrict__ bias,
                                                     unsigned short* __restrict__ Out,
                                                     int M, int N, int K) {
  extern __shared__ char lds[];
  char* sA = lds;              // 2 bufs x 32KB
  char* sB = lds + 65536;      // 2 bufs x 32KB
  int id = blockIdx.x + gridDim.x * (blockIdx.y + gridDim.y * blockIdx.z);
  int e = (id & 7) * 2 + ((id >> 3) & 1);
  int tile = id >> 4;
  int m0 = (tile & 3) * 256, n0 = (tile >> 2) * 256;
  const unsigned short* Ae = A + (size_t)e * aStride;
  const unsigned short* We = WT + (size_t)e * (size_t)N * K;
  int tid = threadIdx.x, lane = tid & 63, w = tid >> 6;  // w = 0..15
  int l15 = lane & 15, l4 = lane >> 4;
  int wr = (w >> 2) * 64;    // output row base 0/64/128/192
  int wc = (w & 3) * 64;     // output col base 0/64/128/192
  f32x4 acc[4][4] = {};
  int nk = K >> 6;

  auto stageA = [&](int buf, int h, int kt) {
    int off = tid * 16;                       // [0,16384) covers 128 rows
    int row = h * 128 + (off >> 7);
    int ss = ((off >> 4) & 7) ^ (row & 7);
    const char* src = (const char*)(Ae + (size_t)(m0 + row) * K + kt * 64) + ss * 16;
    __builtin_amdgcn_global_load_lds((const __attribute__((address_space(1))) void*)src,
        (__attribute__((address_space(3))) void*)(sA + buf * 32768 + h * 16384 + off), 16, 0, 0);
  };
  auto stageB = [&](int buf, int h, int kt) {
    int off = tid * 16;
    int row = h * 128 + (off >> 7);
    int ss = ((off >> 4) & 7) ^ (row & 7);
    const char* src = (const char*)(We + (size_t)(n0 + row) * K + kt * 64) + ss * 16;
    __builtin_amdgcn_global_load_lds((const __attribute__((address_space(1))) void*)src,
        (__attribute__((address_space(3))) void*)(sB + buf * 32768 + h * 16384 + off), 16, 0, 0);
  };
  auto ldA = [&](int buf, int mi, int ks) {
    int row = wr + mi * 16 + l15;             // 0..255
    int sp = (l4 + ks * 4) ^ (row & 7);
    return *(const bf16x8*)(sA + buf * 32768 + row * 128 + sp * 16);
  };
  auto ldB = [&](int buf, int ni, int ks) {
    int row = wc + ni * 16 + l15;             // 0..255
    int sp = (l4 + ks * 4) ^ (row & 7);
    return *(const bf16x8*)(sB + buf * 32768 + row * 128 + sp * 16);
  };

  stageA(0, 0, 0); stageA(0, 1, 0); stageB(0, 0, 0); stageB(0, 1, 0);
  asm volatile("s_waitcnt vmcnt(0)" ::: "memory");
  __builtin_amdgcn_s_barrier();

  for (int t = 0; t < nk; ++t) {
    int cur = t & 1, nxt = cur ^ 1;
    if (t + 1 < nk) {
      stageA(nxt, 0, t + 1); stageA(nxt, 1, t + 1);
      stageB(nxt, 0, t + 1); stageB(nxt, 1, t + 1);
    }
#pragma unroll
    for (int ks = 0; ks < 2; ++ks) {
      bf16x8 bfr[4], afr[4];
#pragma unroll
      for (int ni = 0; ni < 4; ++ni) bfr[ni] = ldB(cur, ni, ks);
#pragma unroll
      for (int mi = 0; mi < 4; ++mi) afr[mi] = ldA(cur, mi, ks);
      __builtin_amdgcn_s_setprio(1);
#pragma unroll
      for (int mi = 0; mi < 4; ++mi)
#pragma unroll
        for (int ni = 0; ni < 4; ++ni)
          acc[mi][ni] = __builtin_amdgcn_mfma_f32_16x16x32_bf16(afr[mi], bfr[ni], acc[mi][ni], 0, 0, 0);
      __builtin_amdgcn_s_setprio(0);
    }
    asm volatile("s_waitcnt vmcnt(0)" ::: "memory");
    __builtin_amdgcn_s_barrier();
  }

  size_t obase = (size_t)e * (size_t)M * N;
#pragma unroll
  for (int mi = 0; mi < 4; ++mi)
#pragma unroll
    for (int ni = 0; ni < 4; ++ni) {
      int col = n0 + wc + ni * 16 + l15;
      float bv = bias[(size_t)e * N + col];
#pragma unroll
      for (int j = 0; j < 4; ++j) {
        int row = m0 + wr + mi * 16 + l4 * 4 + j;
        float v = acc[mi][ni][j] + bv;
        v = (v > 0.f) ? v : 0.01f * v;
        Out[obase + (size_t)row * N + col] = f2bf(v);
      }
    }
}

// ---------------- MFMA bf16 GEMM (128x128, kept for L2) ----------------
template <int ACT, int OBF>
__global__ __launch_bounds__(256) void k_gemm(const unsigned short* __restrict__ A, size_t aStride,
                                              const unsigned short* __restrict__ WT,
                                              const float* __restrict__ bias,
                                              void* __restrict__ Out,
                                              int M, int N, int K) {
  __shared__ __align__(16) unsigned short sA[128 * 32];
  __shared__ __align__(16) unsigned short sB[128 * 32];
  int e = blockIdx.z;
  int m0 = blockIdx.x * 128, n0 = blockIdx.y * 128;
  const unsigned short* Ae = A + (size_t)e * aStride;
  const unsigned short* We = WT + (size_t)e * (size_t)N * K;
  int tid = threadIdx.x, lane = tid & 63, w = tid >> 6;
  int l15 = lane & 15, kh = (lane >> 4) * 8;
  int rsub = lane >> 2;
  int kk = (lane & 3) * 8;
  int wr = (w >> 1) * 64, wc = (w & 1) * 64;
  f32x4 acc[4][4] = {};
  int nk = K >> 5;

  auto stage = [&](int kt) {
#pragma unroll
    for (int c = 0; c < 2; ++c) {
      int chunk = w * 2 + c;
      int row = chunk * 16 + rsub;
      const unsigned short* ga = Ae + (size_t)(m0 + row) * K + kt * 32 + kk;
      __builtin_amdgcn_global_load_lds((const __attribute__((address_space(1))) void*)ga,
                                       (__attribute__((address_space(3))) void*)(&sA[chunk * 512]),
                                       16, 0, 0);
      const unsigned short* gb = We + (size_t)(n0 + row) * K + kt * 32 + kk;
      __builtin_amdgcn_global_load_lds((const __attribute__((address_space(1))) void*)gb,
                                       (__attribute__((address_space(3))) void*)(&sB[chunk * 512]),
                                       16, 0, 0);
    }
  };

  stage(0);
  for (int kt = 0; kt < nk; ++kt) {
    __syncthreads();
    bf16x8 a[4], bb[4];
#pragma unroll
    for (int mi = 0; mi < 4; ++mi)
      a[mi] = *(const bf16x8*)&sA[(wr + mi * 16 + l15) * 32 + kh];
#pragma unroll
    for (int ni = 0; ni < 4; ++ni)
      bb[ni] = *(const bf16x8*)&sB[(wc + ni * 16 + l15) * 32 + kh];
#pragma unroll
    for (int mi = 0; mi < 4; ++mi)
#pragma unroll
      for (int ni = 0; ni < 4; ++ni)
        acc[mi][ni] = __builtin_amdgcn_mfma_f32_16x16x32_bf16(a[mi], bb[ni], acc[mi][ni], 0, 0, 0);
    if (kt + 1 < nk) {
      __syncthreads();
      stage(kt + 1);
    }
  }

  unsigned short* outb = (unsigned short*)Out;
  float* outf = (float*)Out;
  size_t obase = (size_t)e * (size_t)M * N;
#pragma unroll
  for (int mi = 0; mi < 4; ++mi) {
#pragma unroll
    for (int ni = 0; ni < 4; ++ni) {
      int col = n0 + wc + ni * 16 + l15;
      float bv = bias[(size_t)e * N + col];
#pragma unroll
      for (int j = 0; j < 4; ++j) {
        int row = m0 + wr + mi * 16 + (lane >> 4) * 4 + j;
        float v = acc[mi][ni][j] + bv;
        if (ACT) v = (v > 0.f) ? v : 0.01f * v;
        if (OBF) outb[obase + (size_t)row * N + col] = f2bf(v);
        else outf[obase + (size_t)row * N + col] = v;
      }
    }
  }
}

// ---------------- cat recon GEMM with FUSED comb gather (A = g1*eout[i1]+g2*eout[i2]) ----------------
__global__ __launch_bounds__(256) void k_catgemm(const float* __restrict__ eout,
                                                 const unsigned short* __restrict__ cwt,
                                                 const float* __restrict__ cb,
                                                 const float* __restrict__ tg,
                                                 const int* __restrict__ ti,
                                                 float* __restrict__ out1) {
  __shared__ __align__(16) unsigned short sA[2][128 * 32];
  __shared__ __align__(16) unsigned short sB[2][128 * 32];
  int n = blockIdx.z;
  int m0 = blockIdx.x * 128;
  const unsigned short* We = cwt + (size_t)n * 128 * 256;
  int tid = threadIdx.x, lane = tid & 63, w = tid >> 6;
  int l15 = lane & 15, kh = (lane >> 4) * 8;
  int rsub = lane >> 2;
  int kk = (lane & 3) * 8;
  int wr = (w >> 1) * 64, wc = (w & 1) * 64;
  f32x4 acc[4][4] = {};
  const int K = 256, nk = K >> 5;

  // per-lane gather state (fixed across K-tiles)
  float g1v[2], g2v[2];
  const float* p1v[2];
  const float* p2v[2];
#pragma unroll
  for (int c = 0; c < 2; ++c) {
    int row = (w * 2 + c) * 16 + rsub;
    int bb = m0 + row;
    int tk = bb * 64 + 32 + n;
    g1v[c] = tg[(size_t)tk * 2];
    g2v[c] = tg[(size_t)tk * 2 + 1];
    int i1 = ti[(size_t)tk * 2], i2 = ti[(size_t)tk * 2 + 1];
    p1v[c] = eout + ((size_t)i1 * B_ + bb) * D_;
    p2v[c] = eout + ((size_t)i2 * B_ + bb) * D_;
  }

  auto stageA = [&](int buf, int kt) {
#pragma unroll
    for (int c = 0; c < 2; ++c) {
      int row = (w * 2 + c) * 16 + rsub;
      const float* q1 = p1v[c] + kt * 32 + kk;
      const float* q2 = p2v[c] + kt * 32 + kk;
      unsigned short vals[8];
#pragma unroll
      for (int k = 0; k < 8; ++k) vals[k] = f2bf(g1v[c] * q1[k] + g2v[c] * q2[k]);
      *(uint4*)&sA[buf][row * 32 + kk] = *(uint4*)vals;
    }
  };
  auto stageB = [&](int buf, int kt) {
#pragma unroll
    for (int c = 0; c < 2; ++c) {
      int chunk = w * 2 + c;
      int row = chunk * 16 + rsub;
      const unsigned short* gb = We + (size_t)row * K + kt * 32 + kk;
      __builtin_amdgcn_global_load_lds((const __attribute__((address_space(1))) void*)gb,
                                       (__attribute__((address_space(3))) void*)(&sB[buf][chunk * 512]),
                                       16, 0, 0);
    }
  };

  stageA(0, 0);
  stageB(0, 0);
  for (int kt = 0; kt < nk; ++kt) {
    int cur = kt & 1;
    __syncthreads();
    if (kt + 1 < nk) {
      stageA(cur ^ 1, kt + 1);
      stageB(cur ^ 1, kt + 1);
    }
    bf16x8 a[4], bb[4];
#pragma unroll
    for (int mi = 0; mi < 4; ++mi)
      a[mi] = *(const bf16x8*)&sA[cur][(wr + mi * 16 + l15) * 32 + kh];
#pragma unroll
    for (int ni = 0; ni < 4; ++ni)
      bb[ni] = *(const bf16x8*)&sB[cur][(wc + ni * 16 + l15) * 32 + kh];
#pragma unroll
    for (int mi = 0; mi < 4; ++mi)
#pragma unroll
      for (int ni = 0; ni < 4; ++ni)
        acc[mi][ni] = __builtin_amdgcn_mfma_f32_16x16x32_bf16(a[mi], bb[ni], acc[mi][ni], 0, 0, 0);
  }

#pragma unroll
  for (int mi = 0; mi < 4; ++mi) {
#pragma unroll
    for (int ni = 0; ni < 4; ++ni) {
      int col = wc + ni * 16 + l15;
      if (col < V_) {
        float bv = cb[(size_t)n * V_ + col];
#pragma unroll
        for (int j = 0; j < 4; ++j) {
          int row = m0 + wr + mi * 16 + (lane >> 4) * 4 + j;
          out1[((size_t)row * 32 + n) * V_ + col] = acc[mi][ni][j] + bv;
        }
      }
    }
  }
}

// ---------------- num recon: wave-per-8n, coalesced float4 rows + butterfly ----------------
__global__ __launch_bounds__(256) void k_num(const float* __restrict__ eout,
                                             const float* __restrict__ nW,
                                             const float* __restrict__ nb,
                                             const float* __restrict__ tg,
                                             const int* __restrict__ ti,
                                             float* __restrict__ out0) {
  int b = blockIdx.x;
  int lane = threadIdx.x & 63;
  int wv = threadIdx.x >> 6;  // 0..3
#pragma unroll
  for (int q = 0; q < 8; ++q) {
    int n = wv * 8 + q;
    int tk = b * 64 + n;  // s = n for numerical positions
    float g1 = tg[(size_t)tk * 2], g2 = tg[(size_t)tk * 2 + 1];
    int i1 = ti[(size_t)tk * 2], i2 = ti[(size_t)tk * 2 + 1];
    const float4* p1 = (const float4*)(eout + ((size_t)i1 * B_ + b) * D_);
    const float4* p2 = (const float4*)(eout + ((size_t)i2 * B_ + b) * D_);
    const float4* wp = (const float4*)(nW + (size_t)n * D_);
    float4 a = p1[lane], c = p2[lane], ww = wp[lane];
    float acc = fmaf(g1, a.x, g2 * c.x) * ww.x + fmaf(g1, a.y, g2 * c.y) * ww.y +
                fmaf(g1, a.z, g2 * c.z) * ww.z + fmaf(g1, a.w, g2 * c.w) * ww.w;
#pragma unroll
    for (int off = 32; off >= 1; off >>= 1) acc += __shfl_xor(acc, off, 64);
    if (lane == 0) out0[(size_t)b * 32 + n] = nb[n] + acc;
  }
}

extern "C" void kernel_launch(void* const* d_in, const int* in_sizes, int n_in,
                              void* d_out, int out_size, void* d_ws, size_t ws_size,
                              hipStream_t stream) {
  const float* codec = (const float*)d_in[0];
  const int* maskp = (const int*)d_in[1];
  const float* pos_emb = (const float*)d_in[2];
  const float* type_emb = (const float*)d_in[3];
  const float* gW1 = (const float*)d_in[4];
  const float* gb1 = (const float*)d_in[5];
  const float* gW2 = (const float*)d_in[6];
  const float* gb2 = (const float*)d_in[7];
  const float* eW0 = (const float*)d_in[8];
  const float* eb0 = (const float*)d_in[9];
  const float* eW1 = (const float*)d_in[10];
  const float* eb1 = (const float*)d_in[11];
  const float* eW2 = (const float*)d_in[12];
  const float* eb2 = (const float*)d_in[13];
  const float* nW = (const float*)d_in[14];
  const float* nb = (const float*)d_in[15];
  const float* cW = (const float*)d_in[16];
  const float* cb = (const float*)d_in[17];

  char* ws = (char*)d_ws;
  size_t o = 0;
  unsigned short* codecbf = (unsigned short*)(ws + o); o += (size_t)B_ * C_ * 2;
  size_t o_w0t = o;
  unsigned short* w0t = (unsigned short*)(ws + o); o += (size_t)E_ * H_ * C_ * 2;
  unsigned short* w1t = (unsigned short*)(ws + o); o += (size_t)E_ * H_ * H_ * 2;
  unsigned short* w2t = (unsigned short*)(ws + o); o += (size_t)E_ * D_ * H_ * 2;
  size_t o_h0 = o;
  unsigned short* h0 = (unsigned short*)(ws + o); o += (size_t)E_ * B_ * H_ * 2;
  unsigned short* h1 = (unsigned short*)(ws + o); o += (size_t)E_ * B_ * H_ * 2;
  double* cp = (double*)(ws + o); o += (size_t)B_ * 256 * 8;
  double* ptT = (double*)(ws + o); o += (size_t)S_ * 256 * 8;
  float* tg = (float*)(ws + o); o += (size_t)B_ * S_ * 2 * 4;
  int* ti = (int*)(ws + o); o += (size_t)B_ * S_ * 2 * 4;
  double* w2d = (double*)(ws + o); o += 4096 * 8;
  double* w1ld = (double*)(ws + o); o += 256 * 8;
  unsigned short* cwt = (unsigned short*)(ws + o); o += (size_t)32 * 128 * 256 * 2;
  double* pp = (double*)(ws + o); o += (size_t)16 * 64 * 256 * 8;
  int* flagcnt = (int*)(ws + o); o += 256;
  int* flaglist = (int*)(ws + o); o += 8192 * 4;
  float* eout = (float*)(ws + o_w0t);  // overlay: w0t dead after layer-0 GEMM
  (void)o_h0;

  float* out = (float*)d_out;
  float* out_num = out;                                     // B*32
  float* out_cat = out + 32768;                             // B*32*100
  float* out_g = out + 32768 + 3276800;                     // B*S*2
  float* out_i = out_g + (size_t)B_ * S_ * 2;               // B*S*2
  float* out_m = out_i + (size_t)B_ * S_ * 2;               // B*S

  hipLaunchKernelGGL(k_codec_cvt, dim3((B_ * C_) / 256), dim3(256), 0, stream,
                     codec, codecbf, gW2, gW1, w2d, w1ld, flagcnt);
  hipLaunchKernelGGL(k_transpose_bf, dim3(H_ / 32, C_ / 32, E_), dim3(256), 0, stream, eW0, w0t, C_, H_);
  hipLaunchKernelGGL(k_transpose_bf, dim3(H_ / 32, H_ / 32, E_), dim3(256), 0, stream, eW1, w1t, H_, H_);
  hipLaunchKernelGGL(k_transpose_bf, dim3(D_ / 32, H_ / 32, E_), dim3(256), 0, stream, eW2, w2t, H_, D_);
  hipLaunchKernelGGL(k_cwt, dim3(4, 8, 32), dim3(256), 0, stream, cW, cwt);
  hipLaunchKernelGGL(k_codecpart, dim3(B_ / 4), dim3(256), 0, stream, codec, gW1, cp);
  hipLaunchKernelGGL(k_postype_part, dim3(S_, 16), dim3(256), 0, stream, pos_emb, type_emb, gW1, pp);
  hipLaunchKernelGGL(k_postype_red, dim3(S_), dim3(256), 0, stream, pp, gb1, ptT);
  hipLaunchKernelGGL(k_gate, dim3(B_), dim3(256), 0, stream, cp, ptT, gW2, w1ld, gb2,
                     maskp, out_g, out_i, out_m, tg, ti, flagcnt, flaglist);
  hipLaunchKernelGGL(k_gate_fix, dim3(2048), dim3(64), 0, stream, cp, ptT, w2d, w1ld, gb2,
                     maskp, flagcnt, flaglist, out_g, out_i, out_m, tg, ti);
  hipLaunchKernelGGL(k_gemm256, dim3(4, 4, E_), dim3(1024), 131072, stream,
                     codecbf, (size_t)0, w0t, eb0, h0, 1024, 1024, 512);
  hipLaunchKernelGGL(k_gemm256, dim3(4, 4, E_), dim3(1024), 131072, stream,
                     h0, (size_t)(B_ * H_), w1t, eb1, h1, 1024, 1024, 1024);
  hipLaunchKernelGGL((k_gemm<0, 0>), dim3(8, 2, E_), dim3(256), 0, stream,
                     h1, (size_t)(B_ * H_), w2t, eb2, (void*)eout, 1024, 256, 1024);
  hipLaunchKernelGGL(k_num, dim3(B_), dim3(256), 0, stream, eout, nW, nb, tg, ti, out_num);
  hipLaunchKernelGGL(k_catgemm, dim3(8, 1, 32), dim3(256), 0, stream, eout, cwt, cb, tg, ti, out_cat);
}

// Round 23
// 222.355 us; speedup vs baseline: 1.1100x; 1.1100x over previous
//
#include <hip/hip_runtime.h>
#include <hip/hip_bf16.h>

typedef __bf16 bf16x8 __attribute__((ext_vector_type(8)));
typedef float f32x4 __attribute__((ext_vector_type(4)));

static constexpr int B_ = 1024, S_ = 64, C_ = 512, E_ = 16, H_ = 1024, D_ = 256, V_ = 100;
static constexpr int NUMN = 32;

__device__ __forceinline__ unsigned short f2bf(float f) {
  union { float f; unsigned u; } x; x.f = f;
  unsigned r = x.u + 0x7fffu + ((x.u >> 16) & 1u);
  return (unsigned short)(r >> 16);
}

// Abramowitz-Stegun 7.1.26 erf, |err| <= 1.5e-7, branch-free, no libm call.
__device__ __forceinline__ float erf_fast(float x) {
  float ax = fabsf(x);
  float t = 1.0f / fmaf(0.3275911f, ax, 1.0f);
  float p = fmaf(1.061405429f, t, -1.453152027f);
  p = fmaf(p, t, 1.421413741f);
  p = fmaf(p, t, -0.284496736f);
  p = fmaf(p, t, 0.254829592f);
  p = p * t;
  float e = 1.0f - p * __expf(-ax * ax);
  return copysignf(e, x);
}

// ---------------- codec -> bf16  +  gate weight f64 conversion (merged) ----------------
__global__ __launch_bounds__(256) void k_codec_cvt(const float* __restrict__ src,
                                                   unsigned short* __restrict__ dst,
                                                   const float* __restrict__ gW2,
                                                   const float* __restrict__ gW1,
                                                   double* __restrict__ w2d,
                                                   double* __restrict__ w1ld,
                                                   int* __restrict__ flagcnt) {
  int i = blockIdx.x * 256 + threadIdx.x;
  if (i < B_ * C_) dst[i] = f2bf(src[i]);
  if (i < 4096) w2d[i] = (double)gW2[i];
  if (i < 256) w1ld[i] = (double)gW1[(size_t)(3 * C_) * 256 + i];
  if (i == 0) *flagcnt = 0;
}

// ---------------- batched transpose f32[K,N] -> bf16[N,K] ----------------
__global__ __launch_bounds__(256) void k_transpose_bf(const float* __restrict__ W,
                                                      unsigned short* __restrict__ WT,
                                                      int K, int N) {
  __shared__ float t[32][33];
  int e = blockIdx.z;
  const float* We = W + (size_t)e * K * N;
  unsigned short* Te = WT + (size_t)e * N * K;
  int n0 = blockIdx.x * 32, k0 = blockIdx.y * 32;
  int tx = threadIdx.x & 31, ty = threadIdx.x >> 5;  // 32 x 8
#pragma unroll
  for (int i = 0; i < 32; i += 8) t[ty + i][tx] = We[(size_t)(k0 + ty + i) * N + n0 + tx];
  __syncthreads();
#pragma unroll
  for (int i = 0; i < 32; i += 8)
    Te[(size_t)(n0 + ty + i) * K + k0 + tx] = f2bf(t[tx][ty + i]);
}

// ---------------- cW [n][d][v] f32 -> cwt [n][128][256] bf16 (v-padded) ----------------
__global__ __launch_bounds__(256) void k_cwt(const float* __restrict__ cW,
                                             unsigned short* __restrict__ cwt) {
  __shared__ float t[32][33];
  int n = blockIdx.z;
  const float* src = cW + (size_t)n * D_ * V_;
  unsigned short* dst = cwt + (size_t)n * 128 * 256;
  int v0 = blockIdx.x * 32, d0 = blockIdx.y * 32;
  int tx = threadIdx.x & 31, ty = threadIdx.x >> 5;  // 32 x 8
#pragma unroll
  for (int i = 0; i < 32; i += 8) {
    int v = v0 + tx;
    t[ty + i][tx] = (v < V_) ? src[(size_t)(d0 + ty + i) * V_ + v] : 0.f;
  }
  __syncthreads();
#pragma unroll
  for (int i = 0; i < 32; i += 8)
    dst[(size_t)(v0 + ty + i) * 256 + d0 + tx] = f2bf(t[tx][ty + i]);
}

// ---------------- gate: codec part  cp[b,j] = sum_k codec[b,k]*gW1[k,j]  (f64) ----------------
// R21-validated form: grid=1024 (4+ blocks/CU -> latency hidden). Do NOT
// batch b's per block: the f64 chain is latency-bound, not L2-bound (R22
// regression: 4-batch cut grid to 256 -> Occ 10% -> 60us).
__global__ __launch_bounds__(256) void k_codecpart(const float* __restrict__ codec,
                                                   const float* __restrict__ gW1,
                                                   double* __restrict__ cp) {
  int j = threadIdx.x, b = blockIdx.x;
  const float* cb = codec + (size_t)b * C_;
  double a0 = 0, a1 = 0, a2 = 0, a3 = 0;
  for (int k = 0; k < C_; k += 4) {
    a0 += (double)cb[k] * (double)gW1[(size_t)k * 256 + j];
    a1 += (double)cb[k + 1] * (double)gW1[(size_t)(k + 1) * 256 + j];
    a2 += (double)cb[k + 2] * (double)gW1[(size_t)(k + 2) * 256 + j];
    a3 += (double)cb[k + 3] * (double)gW1[(size_t)(k + 3) * 256 + j];
  }
  cp[(size_t)b * 256 + j] = (a0 + a1) + (a2 + a3);
}

// ---------------- gate: pos+type partials, split-K (16 chunks of 32) ----------------
__global__ __launch_bounds__(256) void k_postype_part(const float* __restrict__ pos_emb,
                                                      const float* __restrict__ type_emb,
                                                      const float* __restrict__ gW1,
                                                      double* __restrict__ pp) {
  int j = threadIdx.x;
  int s = blockIdx.x;
  int kc = blockIdx.y;
  int tt = (s >= NUMN) ? 1 : 0;
  double a0 = 0, a1 = 0;
  int k0 = kc * 32;
  for (int kk = 0; kk < 32; kk += 2) {
    int k = k0 + kk;
    a0 += (double)pos_emb[(size_t)s * C_ + k] * (double)gW1[(size_t)(C_ + k) * 256 + j] +
          (double)type_emb[(size_t)tt * C_ + k] * (double)gW1[(size_t)(2 * C_ + k) * 256 + j];
    a1 += (double)pos_emb[(size_t)s * C_ + k + 1] * (double)gW1[(size_t)(C_ + k + 1) * 256 + j] +
          (double)type_emb[(size_t)tt * C_ + k + 1] * (double)gW1[(size_t)(2 * C_ + k + 1) * 256 + j];
  }
  pp[((size_t)kc * 64 + s) * 256 + j] = a0 + a1;
}

// ---------------- reduce partials + gb1 -> ptT [j][s] ----------------
__global__ __launch_bounds__(256) void k_postype_red(const double* __restrict__ pp,
                                                     const float* __restrict__ gb1,
                                                     double* __restrict__ ptT) {
  int j = threadIdx.x;
  int s = blockIdx.x;
  double acc = (double)gb1[j];
#pragma unroll
  for (int kc = 0; kc < 16; ++kc) acc += pp[((size_t)kc * 64 + s) * 256 + j];
  ptT[(size_t)j * 64 + s] = acc;
}

// ---------------- gate bulk: f32 logits + margin flagging (no fallback inline) ----------------
__global__ __launch_bounds__(256) void k_gate(const double* __restrict__ cp,
                                              const double* __restrict__ ptT,
                                              const float* __restrict__ gW2,
                                              const double* __restrict__ w1ld,
                                              const float* __restrict__ gb2,
                                              const int* __restrict__ mask,
                                              float* __restrict__ out_g,
                                              float* __restrict__ out_i,
                                              float* __restrict__ out_m,
                                              float* __restrict__ tg,
                                              int* __restrict__ ti,
                                              int* __restrict__ flagcnt,
                                              int* __restrict__ flaglist) {
  __shared__ float red[3][64][17];
  int b = blockIdx.x;
  int s = threadIdx.x & 63;
  int wv = __builtin_amdgcn_readfirstlane(threadIdx.x >> 6);  // 0..3
  int token = b * 64 + s;
  double mf = (double)mask[token];
  const double* cpb = cp + (size_t)b * 256;
  float acc[16];
#pragma unroll
  for (int e = 0; e < 16; ++e) acc[e] = 0.f;
#pragma unroll 2
  for (int jj = 0; jj < 64; ++jj) {
    int j = wv * 64 + jj;
    double xd = cpb[j] + ptT[(size_t)j * 64 + s] + mf * w1ld[j];
    float x = (float)xd;
    float ef = erf_fast(x * 0.70710678f);
    float h = 0.5f * x * (1.0f + ef);
    const float* w2 = gW2 + (size_t)j * 16;
#pragma unroll
    for (int e = 0; e < 16; ++e) acc[e] = fmaf(h, w2[e], acc[e]);
  }
  if (wv > 0) {
#pragma unroll
    for (int e = 0; e < 16; ++e) red[wv - 1][s][e] = acc[e];
  }
  __syncthreads();
  if (wv == 0) {
    double vp[16];
#pragma unroll
    for (int e = 0; e < 16; ++e)
      vp[e] = (double)((acc[e] + red[0][s][e]) + (red[1][s][e] + red[2][s][e])) + (double)gb2[e];
    // ---- decision margin ----
    double margin;
    if (mf == 0.0) {
      double mn = 1e300;
#pragma unroll
      for (int e = 0; e < 16; ++e) mn = fmin(mn, fabs(vp[e]));
      margin = mn;
    } else {
      double t1 = -1e300, t2 = -1e300, t3 = -1e300;
#pragma unroll
      for (int e = 0; e < 16; ++e) {
        double v = vp[e];
        if (v > t1) { t3 = t2; t2 = t1; t1 = v; }
        else if (v > t2) { t3 = t2; t2 = v; }
        else if (v > t3) { t3 = v; }
      }
      margin = fmin(t1 - t2, t2 - t3);
    }
    if (margin < 1e-4) {
      int idx = atomicAdd(flagcnt, 1);
      if (idx < 8192) flaglist[idx] = token;
    }
    // ---- selection (R6-validated logic) ----
    double v1, v2;
    int i1, i2;
    if (mf == 0.0) {
      int idx[2];
      int c = 0;
      for (int e = 0; e < 16 && c < 2; ++e)
        if (vp[e] > 0.0) idx[c++] = e;
      for (int e = 0; e < 16 && c < 2; ++e)
        if (!(vp[e] > 0.0)) idx[c++] = e;
      i1 = idx[0];
      i2 = idx[1];
      v1 = 0.0;
      v2 = 0.0;
    } else {
      v1 = -1e300; v2 = -1e300; i1 = 0; i2 = 1;
#pragma unroll
      for (int e = 0; e < 16; ++e) {
        double v = vp[e];
        if (v > v1) { v2 = v1; i2 = i1; v1 = v; i1 = e; }
        else if (v > v2) { v2 = v; i2 = e; }
      }
    }
    double ex = exp(v2 - v1);
    double den = 1.0 + ex;
    float g1 = (float)(1.0 / den), g2 = (float)(ex / den);
    out_g[(size_t)token * 2] = g1;
    out_g[(size_t)token * 2 + 1] = g2;
    out_i[(size_t)token * 2] = (float)i1;
    out_i[(size_t)token * 2 + 1] = (float)i2;
    out_m[token] = (float)mf;
    tg[(size_t)token * 2] = g1;
    tg[(size_t)token * 2 + 1] = g2;
    ti[(size_t)token * 2] = i1;
    ti[(size_t)token * 2 + 1] = i2;
  }
}

// ---------------- gate fix: exact f64 recompute of flagged tokens ----------------
__global__ __launch_bounds__(64) void k_gate_fix(const double* __restrict__ cp,
                                                 const double* __restrict__ ptT,
                                                 const double* __restrict__ w2d,
                                                 const double* __restrict__ w1ld,
                                                 const float* __restrict__ gb2,
                                                 const int* __restrict__ mask,
                                                 const int* __restrict__ flagcnt,
                                                 const int* __restrict__ flaglist,
                                                 float* __restrict__ out_g,
                                                 float* __restrict__ out_i,
                                                 float* __restrict__ out_m,
                                                 float* __restrict__ tg,
                                                 int* __restrict__ ti) {
  int cnt = *flagcnt;
  if (cnt > 8192) cnt = 8192;
  int lane = threadIdx.x;
  for (int fi = blockIdx.x; fi < cnt; fi += gridDim.x) {
    int token = flaglist[fi];
    int b = token >> 6, sf = token & 63;
    double mf = (double)mask[token];
    const double* cpb = cp + (size_t)b * 256;
    double facc[16];
#pragma unroll
    for (int e = 0; e < 16; ++e) facc[e] = 0.0;
#pragma unroll
    for (int jj = 0; jj < 4; ++jj) {
      int j = jj * 64 + lane;
      double x = cpb[j] + ptT[(size_t)j * 64 + sf] + mf * w1ld[j];
      double h = 0.5 * x * (1.0 + erf(x * 0.70710678118654752440));
      const double* w2 = w2d + (size_t)j * 16;
#pragma unroll
      for (int e = 0; e < 16; ++e) facc[e] += h * w2[e];
    }
#pragma unroll
    for (int off = 32; off >= 1; off >>= 1) {
#pragma unroll
      for (int e = 0; e < 16; ++e) facc[e] += __shfl_xor(facc[e], off, 64);
    }
    if (lane == 0) {
      double vp[16];
#pragma unroll
      for (int e = 0; e < 16; ++e) vp[e] = facc[e] + (double)gb2[e];
      double v1, v2;
      int i1, i2;
      if (mf == 0.0) {
        int idx[2];
        int c = 0;
        for (int e = 0; e < 16 && c < 2; ++e)
          if (vp[e] > 0.0) idx[c++] = e;
        for (int e = 0; e < 16 && c < 2; ++e)
          if (!(vp[e] > 0.0)) idx[c++] = e;
        i1 = idx[0];
        i2 = idx[1];
        v1 = 0.0;
        v2 = 0.0;
      } else {
        v1 = -1e300; v2 = -1e300; i1 = 0; i2 = 1;
#pragma unroll
        for (int e = 0; e < 16; ++e) {
          double v = vp[e];
          if (v > v1) { v2 = v1; i2 = i1; v1 = v; i1 = e; }
          else if (v > v2) { v2 = v; i2 = e; }
        }
      }
      double ex = exp(v2 - v1);
      double den = 1.0 + ex;
      float g1 = (float)(1.0 / den), g2 = (float)(ex / den);
      out_g[(size_t)token * 2] = g1;
      out_g[(size_t)token * 2 + 1] = g2;
      out_i[(size_t)token * 2] = (float)i1;
      out_i[(size_t)token * 2 + 1] = (float)i2;
      out_m[token] = (float)mf;
      tg[(size_t)token * 2] = g1;
      tg[(size_t)token * 2 + 1] = g2;
      ti[(size_t)token * 2] = i1;
      ti[(size_t)token * 2 + 1] = i2;
    }
  }
}

// ---------------- 256x256 MFMA GEMM: 16 waves (64x64 each), BK=64, dbuf, 1 drain/tile ----------------
__global__ __launch_bounds__(1024, 1) void k_gemm256(const unsigned short* __restrict__ A, size_t aStride,
                                                     const unsigned short* __restrict__ WT,
                                                     const float* __restrict__ bias,
                                                     unsigned short* __restrict__ Out,
                                                     int M, int N, int K) {
  extern __shared__ char lds[];
  char* sA = lds;              // 2 bufs x 32KB
  char* sB = lds + 65536;      // 2 bufs x 32KB
  int id = blockIdx.x + gridDim.x * (blockIdx.y + gridDim.y * blockIdx.z);
  int e = (id & 7) * 2 + ((id >> 3) & 1);
  int tile = id >> 4;
  int m0 = (tile & 3) * 256, n0 = (tile >> 2) * 256;
  const unsigned short* Ae = A + (size_t)e * aStride;
  const unsigned short* We = WT + (size_t)e * (size_t)N * K;
  int tid = threadIdx.x, lane = tid & 63, w = tid >> 6;  // w = 0..15
  int l15 = lane & 15, l4 = lane >> 4;
  int wr = (w >> 2) * 64;    // output row base 0/64/128/192
  int wc = (w & 3) * 64;     // output col base 0/64/128/192
  f32x4 acc[4][4] = {};
  int nk = K >> 6;

  auto stageA = [&](int buf, int h, int kt) {
    int off = tid * 16;                       // [0,16384) covers 128 rows
    int row = h * 128 + (off >> 7);
    int ss = ((off >> 4) & 7) ^ (row & 7);
    const char* src = (const char*)(Ae + (size_t)(m0 + row) * K + kt * 64) + ss * 16;
    __builtin_amdgcn_global_load_lds((const __attribute__((address_space(1))) void*)src,
        (__attribute__((address_space(3))) void*)(sA + buf * 32768 + h * 16384 + off), 16, 0, 0);
  };
  auto stageB = [&](int buf, int h, int kt) {
    int off = tid * 16;
    int row = h * 128 + (off >> 7);
    int ss = ((off >> 4) & 7) ^ (row & 7);
    const char* src = (const char*)(We + (size_t)(n0 + row) * K + kt * 64) + ss * 16;
    __builtin_amdgcn_global_load_lds((const __attribute__((address_space(1))) void*)src,
        (__attribute__((address_space(3))) void*)(sB + buf * 32768 + h * 16384 + off), 16, 0, 0);
  };
  auto ldA = [&](int buf, int mi, int ks) {
    int row = wr + mi * 16 + l15;             // 0..255
    int sp = (l4 + ks * 4) ^ (row & 7);
    return *(const bf16x8*)(sA + buf * 32768 + row * 128 + sp * 16);
  };
  auto ldB = [&](int buf, int ni, int ks) {
    int row = wc + ni * 16 + l15;             // 0..255
    int sp = (l4 + ks * 4) ^ (row & 7);
    return *(const bf16x8*)(sB + buf * 32768 + row * 128 + sp * 16);
  };

  stageA(0, 0, 0); stageA(0, 1, 0); stageB(0, 0, 0); stageB(0, 1, 0);
  asm volatile("s_waitcnt vmcnt(0)" ::: "memory");
  __builtin_amdgcn_s_barrier();

  for (int t = 0; t < nk; ++t) {
    int cur = t & 1, nxt = cur ^ 1;
    if (t + 1 < nk) {
      stageA(nxt, 0, t + 1); stageA(nxt, 1, t + 1);
      stageB(nxt, 0, t + 1); stageB(nxt, 1, t + 1);
    }
#pragma unroll
    for (int ks = 0; ks < 2; ++ks) {
      bf16x8 bfr[4], afr[4];
#pragma unroll
      for (int ni = 0; ni < 4; ++ni) bfr[ni] = ldB(cur, ni, ks);
#pragma unroll
      for (int mi = 0; mi < 4; ++mi) afr[mi] = ldA(cur, mi, ks);
      __builtin_amdgcn_s_setprio(1);
#pragma unroll
      for (int mi = 0; mi < 4; ++mi)
#pragma unroll
        for (int ni = 0; ni < 4; ++ni)
          acc[mi][ni] = __builtin_amdgcn_mfma_f32_16x16x32_bf16(afr[mi], bfr[ni], acc[mi][ni], 0, 0, 0);
      __builtin_amdgcn_s_setprio(0);
    }
    asm volatile("s_waitcnt vmcnt(0)" ::: "memory");
    __builtin_amdgcn_s_barrier();
  }

  size_t obase = (size_t)e * (size_t)M * N;
#pragma unroll
  for (int mi = 0; mi < 4; ++mi)
#pragma unroll
    for (int ni = 0; ni < 4; ++ni) {
      int col = n0 + wc + ni * 16 + l15;
      float bv = bias[(size_t)e * N + col];
#pragma unroll
      for (int j = 0; j < 4; ++j) {
        int row = m0 + wr + mi * 16 + l4 * 4 + j;
        float v = acc[mi][ni][j] + bv;
        v = (v > 0.f) ? v : 0.01f * v;
        Out[obase + (size_t)row * N + col] = f2bf(v);
      }
    }
}

// ---------------- MFMA bf16 GEMM (128x128, kept for L2) ----------------
template <int ACT, int OBF>
__global__ __launch_bounds__(256) void k_gemm(const unsigned short* __restrict__ A, size_t aStride,
                                              const unsigned short* __restrict__ WT,
                                              const float* __restrict__ bias,
                                              void* __restrict__ Out,
                                              int M, int N, int K) {
  __shared__ __align__(16) unsigned short sA[128 * 32];
  __shared__ __align__(16) unsigned short sB[128 * 32];
  int e = blockIdx.z;
  int m0 = blockIdx.x * 128, n0 = blockIdx.y * 128;
  const unsigned short* Ae = A + (size_t)e * aStride;
  const unsigned short* We = WT + (size_t)e * (size_t)N * K;
  int tid = threadIdx.x, lane = tid & 63, w = tid >> 6;
  int l15 = lane & 15, kh = (lane >> 4) * 8;
  int rsub = lane >> 2;
  int kk = (lane & 3) * 8;
  int wr = (w >> 1) * 64, wc = (w & 1) * 64;
  f32x4 acc[4][4] = {};
  int nk = K >> 5;

  auto stage = [&](int kt) {
#pragma unroll
    for (int c = 0; c < 2; ++c) {
      int chunk = w * 2 + c;
      int row = chunk * 16 + rsub;
      const unsigned short* ga = Ae + (size_t)(m0 + row) * K + kt * 32 + kk;
      __builtin_amdgcn_global_load_lds((const __attribute__((address_space(1))) void*)ga,
                                       (__attribute__((address_space(3))) void*)(&sA[chunk * 512]),
                                       16, 0, 0);
      const unsigned short* gb = We + (size_t)(n0 + row) * K + kt * 32 + kk;
      __builtin_amdgcn_global_load_lds((const __attribute__((address_space(1))) void*)gb,
                                       (__attribute__((address_space(3))) void*)(&sB[chunk * 512]),
                                       16, 0, 0);
    }
  };

  stage(0);
  for (int kt = 0; kt < nk; ++kt) {
    __syncthreads();
    bf16x8 a[4], bb[4];
#pragma unroll
    for (int mi = 0; mi < 4; ++mi)
      a[mi] = *(const bf16x8*)&sA[(wr + mi * 16 + l15) * 32 + kh];
#pragma unroll
    for (int ni = 0; ni < 4; ++ni)
      bb[ni] = *(const bf16x8*)&sB[(wc + ni * 16 + l15) * 32 + kh];
#pragma unroll
    for (int mi = 0; mi < 4; ++mi)
#pragma unroll
      for (int ni = 0; ni < 4; ++ni)
        acc[mi][ni] = __builtin_amdgcn_mfma_f32_16x16x32_bf16(a[mi], bb[ni], acc[mi][ni], 0, 0, 0);
    if (kt + 1 < nk) {
      __syncthreads();
      stage(kt + 1);
    }
  }

  unsigned short* outb = (unsigned short*)Out;
  float* outf = (float*)Out;
  size_t obase = (size_t)e * (size_t)M * N;
#pragma unroll
  for (int mi = 0; mi < 4; ++mi) {
#pragma unroll
    for (int ni = 0; ni < 4; ++ni) {
      int col = n0 + wc + ni * 16 + l15;
      float bv = bias[(size_t)e * N + col];
#pragma unroll
      for (int j = 0; j < 4; ++j) {
        int row = m0 + wr + mi * 16 + (lane >> 4) * 4 + j;
        float v = acc[mi][ni][j] + bv;
        if (ACT) v = (v > 0.f) ? v : 0.01f * v;
        if (OBF) outb[obase + (size_t)row * N + col] = f2bf(v);
        else outf[obase + (size_t)row * N + col] = v;
      }
    }
  }
}

// ---------------- cat recon GEMM with FUSED comb gather (A = g1*eout[i1]+g2*eout[i2]) ----------------
__global__ __launch_bounds__(256) void k_catgemm(const float* __restrict__ eout,
                                                 const unsigned short* __restrict__ cwt,
                                                 const float* __restrict__ cb,
                                                 const float* __restrict__ tg,
                                                 const int* __restrict__ ti,
                                                 float* __restrict__ out1) {
  __shared__ __align__(16) unsigned short sA[2][128 * 32];
  __shared__ __align__(16) unsigned short sB[2][128 * 32];
  int n = blockIdx.z;
  int m0 = blockIdx.x * 128;
  const unsigned short* We = cwt + (size_t)n * 128 * 256;
  int tid = threadIdx.x, lane = tid & 63, w = tid >> 6;
  int l15 = lane & 15, kh = (lane >> 4) * 8;
  int rsub = lane >> 2;
  int kk = (lane & 3) * 8;
  int wr = (w >> 1) * 64, wc = (w & 1) * 64;
  f32x4 acc[4][4] = {};
  const int K = 256, nk = K >> 5;

  // per-lane gather state (fixed across K-tiles)
  float g1v[2], g2v[2];
  const float* p1v[2];
  const float* p2v[2];
#pragma unroll
  for (int c = 0; c < 2; ++c) {
    int row = (w * 2 + c) * 16 + rsub;
    int bb = m0 + row;
    int tk = bb * 64 + 32 + n;
    g1v[c] = tg[(size_t)tk * 2];
    g2v[c] = tg[(size_t)tk * 2 + 1];
    int i1 = ti[(size_t)tk * 2], i2 = ti[(size_t)tk * 2 + 1];
    p1v[c] = eout + ((size_t)i1 * B_ + bb) * D_;
    p2v[c] = eout + ((size_t)i2 * B_ + bb) * D_;
  }

  auto stageA = [&](int buf, int kt) {
#pragma unroll
    for (int c = 0; c < 2; ++c) {
      int row = (w * 2 + c) * 16 + rsub;
      const float* q1 = p1v[c] + kt * 32 + kk;
      const float* q2 = p2v[c] + kt * 32 + kk;
      unsigned short vals[8];
#pragma unroll
      for (int k = 0; k < 8; ++k) vals[k] = f2bf(g1v[c] * q1[k] + g2v[c] * q2[k]);
      *(uint4*)&sA[buf][row * 32 + kk] = *(uint4*)vals;
    }
  };
  auto stageB = [&](int buf, int kt) {
#pragma unroll
    for (int c = 0; c < 2; ++c) {
      int chunk = w * 2 + c;
      int row = chunk * 16 + rsub;
      const unsigned short* gb = We + (size_t)row * K + kt * 32 + kk;
      __builtin_amdgcn_global_load_lds((const __attribute__((address_space(1))) void*)gb,
                                       (__attribute__((address_space(3))) void*)(&sB[buf][chunk * 512]),
                                       16, 0, 0);
    }
  };

  stageA(0, 0);
  stageB(0, 0);
  for (int kt = 0; kt < nk; ++kt) {
    int cur = kt & 1;
    __syncthreads();
    if (kt + 1 < nk) {
      stageA(cur ^ 1, kt + 1);
      stageB(cur ^ 1, kt + 1);
    }
    bf16x8 a[4], bb[4];
#pragma unroll
    for (int mi = 0; mi < 4; ++mi)
      a[mi] = *(const bf16x8*)&sA[cur][(wr + mi * 16 + l15) * 32 + kh];
#pragma unroll
    for (int ni = 0; ni < 4; ++ni)
      bb[ni] = *(const bf16x8*)&sB[cur][(wc + ni * 16 + l15) * 32 + kh];
#pragma unroll
    for (int mi = 0; mi < 4; ++mi)
#pragma unroll
      for (int ni = 0; ni < 4; ++ni)
        acc[mi][ni] = __builtin_amdgcn_mfma_f32_16x16x32_bf16(a[mi], bb[ni], acc[mi][ni], 0, 0, 0);
  }

#pragma unroll
  for (int mi = 0; mi < 4; ++mi) {
#pragma unroll
    for (int ni = 0; ni < 4; ++ni) {
      int col = wc + ni * 16 + l15;
      if (col < V_) {
        float bv = cb[(size_t)n * V_ + col];
#pragma unroll
        for (int j = 0; j < 4; ++j) {
          int row = m0 + wr + mi * 16 + (lane >> 4) * 4 + j;
          out1[((size_t)row * 32 + n) * V_ + col] = acc[mi][ni][j] + bv;
        }
      }
    }
  }
}

// ---------------- num recon: wave-per-8n, coalesced float4 rows + butterfly ----------------
__global__ __launch_bounds__(256) void k_num(const float* __restrict__ eout,
                                             const float* __restrict__ nW,
                                             const float* __restrict__ nb,
                                             const float* __restrict__ tg,
                                             const int* __restrict__ ti,
                                             float* __restrict__ out0) {
  int b = blockIdx.x;
  int lane = threadIdx.x & 63;
  int wv = threadIdx.x >> 6;  // 0..3
#pragma unroll
  for (int q = 0; q < 8; ++q) {
    int n = wv * 8 + q;
    int tk = b * 64 + n;  // s = n for numerical positions
    float g1 = tg[(size_t)tk * 2], g2 = tg[(size_t)tk * 2 + 1];
    int i1 = ti[(size_t)tk * 2], i2 = ti[(size_t)tk * 2 + 1];
    const float4* p1 = (const float4*)(eout + ((size_t)i1 * B_ + b) * D_);
    const float4* p2 = (const float4*)(eout + ((size_t)i2 * B_ + b) * D_);
    const float4* wp = (const float4*)(nW + (size_t)n * D_);
    float4 a = p1[lane], c = p2[lane], ww = wp[lane];
    float acc = fmaf(g1, a.x, g2 * c.x) * ww.x + fmaf(g1, a.y, g2 * c.y) * ww.y +
                fmaf(g1, a.z, g2 * c.z) * ww.z + fmaf(g1, a.w, g2 * c.w) * ww.w;
#pragma unroll
    for (int off = 32; off >= 1; off >>= 1) acc += __shfl_xor(acc, off, 64);
    if (lane == 0) out0[(size_t)b * 32 + n] = nb[n] + acc;
  }
}

extern "C" void kernel_launch(void* const* d_in, const int* in_sizes, int n_in,
                              void* d_out, int out_size, void* d_ws, size_t ws_size,
                              hipStream_t stream) {
  const float* codec = (const float*)d_in[0];
  const int* maskp = (const int*)d_in[1];
  const float* pos_emb = (const float*)d_in[2];
  const float* type_emb = (const float*)d_in[3];
  const float* gW1 = (const float*)d_in[4];
  const float* gb1 = (const float*)d_in[5];
  const float* gW2 = (const float*)d_in[6];
  const float* gb2 = (const float*)d_in[7];
  const float* eW0 = (const float*)d_in[8];
  const float* eb0 = (const float*)d_in[9];
  const float* eW1 = (const float*)d_in[10];
  const float* eb1 = (const float*)d_in[11];
  const float* eW2 = (const float*)d_in[12];
  const float* eb2 = (const float*)d_in[13];
  const float* nW = (const float*)d_in[14];
  const float* nb = (const float*)d_in[15];
  const float* cW = (const float*)d_in[16];
  const float* cb = (const float*)d_in[17];

  char* ws = (char*)d_ws;
  size_t o = 0;
  unsigned short* codecbf = (unsigned short*)(ws + o); o += (size_t)B_ * C_ * 2;
  size_t o_w0t = o;
  unsigned short* w0t = (unsigned short*)(ws + o); o += (size_t)E_ * H_ * C_ * 2;
  unsigned short* w1t = (unsigned short*)(ws + o); o += (size_t)E_ * H_ * H_ * 2;
  unsigned short* w2t = (unsigned short*)(ws + o); o += (size_t)E_ * D_ * H_ * 2;
  size_t o_h0 = o;
  unsigned short* h0 = (unsigned short*)(ws + o); o += (size_t)E_ * B_ * H_ * 2;
  unsigned short* h1 = (unsigned short*)(ws + o); o += (size_t)E_ * B_ * H_ * 2;
  double* cp = (double*)(ws + o); o += (size_t)B_ * 256 * 8;
  double* ptT = (double*)(ws + o); o += (size_t)S_ * 256 * 8;
  float* tg = (float*)(ws + o); o += (size_t)B_ * S_ * 2 * 4;
  int* ti = (int*)(ws + o); o += (size_t)B_ * S_ * 2 * 4;
  double* w2d = (double*)(ws + o); o += 4096 * 8;
  double* w1ld = (double*)(ws + o); o += 256 * 8;
  unsigned short* cwt = (unsigned short*)(ws + o); o += (size_t)32 * 128 * 256 * 2;
  double* pp = (double*)(ws + o); o += (size_t)16 * 64 * 256 * 8;
  int* flagcnt = (int*)(ws + o); o += 256;
  int* flaglist = (int*)(ws + o); o += 8192 * 4;
  float* eout = (float*)(ws + o_w0t);  // overlay: w0t dead after layer-0 GEMM
  (void)o_h0;

  float* out = (float*)d_out;
  float* out_num = out;                                     // B*32
  float* out_cat = out + 32768;                             // B*32*100
  float* out_g = out + 32768 + 3276800;                     // B*S*2
  float* out_i = out_g + (size_t)B_ * S_ * 2;               // B*S*2
  float* out_m = out_i + (size_t)B_ * S_ * 2;               // B*S

  hipLaunchKernelGGL(k_codec_cvt, dim3((B_ * C_) / 256), dim3(256), 0, stream,
                     codec, codecbf, gW2, gW1, w2d, w1ld, flagcnt);
  hipLaunchKernelGGL(k_transpose_bf, dim3(H_ / 32, C_ / 32, E_), dim3(256), 0, stream, eW0, w0t, C_, H_);
  hipLaunchKernelGGL(k_transpose_bf, dim3(H_ / 32, H_ / 32, E_), dim3(256), 0, stream, eW1, w1t, H_, H_);
  hipLaunchKernelGGL(k_transpose_bf, dim3(D_ / 32, H_ / 32, E_), dim3(256), 0, stream, eW2, w2t, H_, D_);
  hipLaunchKernelGGL(k_cwt, dim3(4, 8, 32), dim3(256), 0, stream, cW, cwt);
  hipLaunchKernelGGL(k_codecpart, dim3(B_), dim3(256), 0, stream, codec, gW1, cp);
  hipLaunchKernelGGL(k_postype_part, dim3(S_, 16), dim3(256), 0, stream, pos_emb, type_emb, gW1, pp);
  hipLaunchKernelGGL(k_postype_red, dim3(S_), dim3(256), 0, stream, pp, gb1, ptT);
  hipLaunchKernelGGL(k_gate, dim3(B_), dim3(256), 0, stream, cp, ptT, gW2, w1ld, gb2,
                     maskp, out_g, out_i, out_m, tg, ti, flagcnt, flaglist);
  hipLaunchKernelGGL(k_gate_fix, dim3(2048), dim3(64), 0, stream, cp, ptT, w2d, w1ld, gb2,
                     maskp, flagcnt, flaglist, out_g, out_i, out_m, tg, ti);
  hipLaunchKernelGGL(k_gemm256, dim3(4, 4, E_), dim3(1024), 131072, stream,
                     codecbf, (size_t)0, w0t, eb0, h0, 1024, 1024, 512);
  hipLaunchKernelGGL(k_gemm256, dim3(4, 4, E_), dim3(1024), 131072, stream,
                     h0, (size_t)(B_ * H_), w1t, eb1, h1, 1024, 1024, 1024);
  hipLaunchKernelGGL((k_gemm<0, 0>), dim3(8, 2, E_), dim3(256), 0, stream,
                     h1, (size_t)(B_ * H_), w2t, eb2, (void*)eout, 1024, 256, 1024);
  hipLaunchKernelGGL(k_num, dim3(B_), dim3(256), 0, stream, eout, nW, nb, tg, ti, out_num);
  hipLaunchKernelGGL(k_catgemm, dim3(8, 1, 32), dim3(256), 0, stream, eout, cwt, cb, tg, ti, out_cat);
}